// Round 14
// baseline (239.663 us; speedup 1.0000x reference)
//
#include <hip/hip_runtime.h>
#include <math.h>

#define TOPK 13
#define PI_F 3.14159265358979323846f
#define RPB 4     // gt-rows per block
#define NC 4      // anchor chunks per row
#define CAP 64    // per-row positive-candidate LDS buffer

typedef unsigned int u32;
typedef unsigned long long u64;

// monotone float -> uint mapping matching XLA total order
__device__ __forceinline__ u32 ford(float f) {
    u32 u = __float_as_uint(f);
    return (u & 0x80000000u) ? ~u : (u | 0x80000000u);
}
__device__ __forceinline__ float funord(u32 o) {
    u32 u = (o & 0x80000000u) ? (o & 0x7FFFFFFFu) : ~o;
    return __uint_as_float(u);
}

__device__ __forceinline__ float iou_fn(float4 g, float4 p) {
    float ltx = fmaxf(g.x, p.x), lty = fmaxf(g.y, p.y);
    float rbx = fminf(g.z, p.z), rby = fminf(g.w, p.w);
    float inter = fmaxf(rbx - ltx, 0.0f) * fmaxf(rby - lty, 0.0f);
    float a1 = fmaxf(g.z - g.x, 0.0f) * fmaxf(g.w - g.y, 0.0f);
    float a2 = fmaxf(p.z - p.x, 0.0f) * fmaxf(p.w - p.y, 0.0f);
    return inter / (((a1 + a2) - inter) + 1e-9f);
}

struct RowParams { float av, bar, offc, mx, mn; };

__device__ __forceinline__ RowParams row_params(float4 g) {
    float w = g.z - g.x, h = g.w - g.y;
    float ar = w / (h + 1e-5f);
    float ia = 1.0f / ar;
    RowParams rp;
    rp.av = ia / (2.0f - ia);
    rp.bar = 2.0f / ar;
    rp.offc = PI_F * (1.0f - 2.0f / (2.0f * ar));
    rp.mx = 0.5f + 0.5f * cosf(rp.offc);
    rp.mn = 0.5f + 0.5f * cosf(rp.bar * 90.0f / 180.0f * PI_F + rp.offc);
    return rp;
}

__device__ __forceinline__ float ang_measure(const RowParams& rp, float theta) {
    float cfv = 0.5f + 0.5f * cosf(rp.bar * theta / 180.0f * PI_F + rp.offc);
    float r = (cfv - rp.mn) / (rp.mx - rp.mn) * (1.0f - rp.av) + rp.av;
    return isnan(r) ? 0.0f : r;
}

// align in exact reference op order: (s**1 * iou**5) * ang**3, left-assoc
__device__ __forceinline__ float align_fn(float s, float iou, float r) {
    float iou2 = iou * iou;
    float iou5 = (iou2 * iou2) * iou;
    float r3 = (r * r) * r;
    return (s * iou5) * r3;
}

__global__ void k0_init(int* cnt, int* assign1, u32* pam, u32* pov, int* rowdone,
                        int BA, int BN) {
    int t = blockIdx.x * blockDim.x + threadIdx.x;
    if (t < BA) { cnt[t] = 0; assign1[t] = -1; }
    if (t < BN) { pam[t] = 0x80000000u; pov[t] = 0x80000000u; rowdone[t] = 0; }
}

// ---------------------------------------------------------------------------
// k1: one block per (batch, 4-row group, anchor chunk) — the r13 kernel
// (42 µs, passed) with k1m_merge FOLDED IN via last-arriving-block merge:
// each (row,chunk) wave publishes its sorted 13-list with device-scope
// atomicExch stores, __threadfence (release), then bumps rowdone[bi]; the
// wave observing old==NC-1 __threadfence's (acquire) and performs the exact
// 52-key merge (atomic-read loads — device-scope atomics are coherent
// across XCDs, G16) and fires the same cnt/assign1 atomics k1m did.
// Removes one kernel launch + gap (r13 lesson: the k1m launch cost more
// than the work it contained). Everything else byte-identical to r13.
// ---------------------------------------------------------------------------
__global__ __launch_bounds__(256)
void k1_topk(const float* __restrict__ scores, const float* __restrict__ pbox,
             const float* __restrict__ pang, const float* __restrict__ anc,
             const int* __restrict__ glab, const float* __restrict__ gbox,
             const float* __restrict__ gang, const float* __restrict__ mgt,
             u64* __restrict__ wslist, int* __restrict__ rowdone,
             int* __restrict__ cnt, int* __restrict__ assign1,
             float* __restrict__ out,
             int bs, int A, int n, int C) {
    int j = blockIdx.x;
    int b = j % bs;                 // XCD spread
    int r2 = j / bs;
    int NG = (n + RPB - 1) / RPB;
    int rg = r2 % NG;
    int c0 = r2 / NG;
    int i0 = rg * RPB;
    int tid = threadIdx.x;
    int BA = bs * A;

    // ts zero-fill chunk for this block (hidden under the anchor scan)
    int nF4 = BA * (C / 4);
    int zCH = (nF4 + gridDim.x - 1) / gridDim.x;
    int zBeg = j * zCH + tid;
    int zEnd = min(j * zCH + zCH, nF4);
    float4* tsf4 = (float4*)(out + (size_t)BA * 6);
    const float4 z4 = make_float4(0.0f, 0.0f, 0.0f, 0.0f);

    __shared__ u64 posL[RPB][CAP];
    __shared__ u64 zdump[RPB][256];
    __shared__ int pc[RPB];
    if (tid < RPB) pc[tid] = 0;

    // per-row state (indexed only by unrolled/static indices)
    float4 g[RPB];
    float rpav[RPB], rpbar[RPB], rpoff[RPB], rpmx[RPB], rpmn[RPB];
    float ga[RPB];
    int lab[RPB];
    bool act[RPB];
#pragma unroll
    for (int r = 0; r < RPB; ++r) {
        int i = i0 + r;
        act[r] = false;
        g[r] = make_float4(0.0f, 0.0f, 0.0f, 0.0f);
        ga[r] = 0.0f; lab[r] = 0;
        rpav[r] = rpbar[r] = rpoff[r] = rpmx[r] = rpmn[r] = 0.0f;
        if (i < n) {
            int bi = b * n + i;
            if (mgt[bi] > 0.0f) {       // masked rows contribute nothing
                act[r] = true;
                g[r] = ((const float4*)gbox)[bi];
                RowParams rp = row_params(g[r]);
                rpav[r] = rp.av; rpbar[r] = rp.bar; rpoff[r] = rp.offc;
                rpmx[r] = rp.mx; rpmn[r] = rp.mn;
                ga[r] = gang[bi];
                lab[r] = glab[bi];
            }
        }
    }
    __syncthreads();   // pc init visible before LDS atomics

    const float4* pb = ((const float4*)pbox) + (size_t)b * A;
    const float* pa = pang + (size_t)b * A;
    const float2* ac = (const float2*)anc;
    const float* scb = scores + (size_t)b * A * C;

    int CS = (A + NC - 1) / NC;       // 2100 for A=8400
    int start = c0 * CS;
    int end = min(start + CS, A);
    int clampE = end - 1;

    u64 zkey[RPB];
#pragma unroll
    for (int r = 0; r < RPB; ++r) zkey[r] = 0ull;

    // prologue: stage iteration 0 (CS > 256, so start+tid < end)
    int a = start + tid;
    float4 p = pb[a];
    float pav = pa[a];
    float2 apt = ac[a];

    // Exactness of the conditional-r path (reference v = align*in_gts,
    // align = (s*iou^5)*r^3, s>=0, iou>=0, r finite after NaN-replace):
    //  - !inGt or iou==0  -> v = +/-0 with sign(r); selectable only if +0.
    //  - inGt && iou>0    -> r>0: v = align (>0 -> positive; ==+0 -> zero);
    //                       r==0: +0; r<0: v<0 never selectable.
    //  sign(r) only consumed while zkey[r] unset -> cosf skipped afterwards.
    int nit = (end - start + 255) >> 8;   // 9
    for (int it = 0; it < nit; ++it) {
        int an = a + 256;
        int can = min(an, clampE);
        float4 p2 = pb[can];
        float pav2 = pa[can];
        float2 apt2 = ac[can];
        // hidden zero-fill stores (fire-and-forget; 2x9=18 >= ~11 per thread)
        if (zBeg < zEnd) { tsf4[zBeg] = z4; zBeg += 256; }
        if (zBeg < zEnd) { tsf4[zBeg] = z4; zBeg += 256; }
        if (a < end) {
#pragma unroll
            for (int r = 0; r < RPB; ++r) {
                if (!act[r]) continue;   // block-uniform
                float mnv = fminf(fminf(apt.x - g[r].x, apt.y - g[r].y),
                                  fminf(g[r].z - apt.x, g[r].w - apt.y));
                float iou = iou_fn(g[r], p);
                bool na = (mnv > 1e-9f) && (iou > 0.0f);
                if (na || zkey[r] == 0ull) {
                    RowParams rp;
                    rp.av = rpav[r]; rp.bar = rpbar[r]; rp.offc = rpoff[r];
                    rp.mx = rpmx[r]; rp.mn = rpmn[r];
                    float th = fabsf(ga[r] - pav);
                    float rr = ang_measure(rp, th);
                    bool zc;
                    if (na && rr > 0.0f) {
                        float s = scb[(size_t)a * C + lab[r]];  // scattered, rare
                        float v = align_fn(s, iou, rr);
                        if (v > 0.0f) {
                            zc = false;
                            u64 key = ((u64)ford(v) << 32) | (u64)(0xFFFFFFFFu - (u32)a);
                            int idx = atomicAdd(&pc[r], 1);
                            if (idx < CAP) posL[r][idx] = key;
                        } else zc = true;   // s==0 or iou^5 underflow -> +0 exactly
                    } else zc = (rr >= 0.0f);  // v == sign(r)*0
                    if (zc && zkey[r] == 0ull)
                        zkey[r] = (0x80000000ull << 32) | (u64)(0xFFFFFFFFu - (u32)a);
                }
            }
        }
        a = an; p = p2; pav = pav2; apt = apt2;
    }
    for (; zBeg < zEnd; zBeg += 256) tsf4[zBeg] = z4;  // drain

#pragma unroll
    for (int r = 0; r < RPB; ++r) zdump[r][tid] = zkey[r];
    __syncthreads();

    int lane = tid & 63, wv = tid >> 6;

    // wave w extracts row w's chunk top-13 -> sorted 13-list in workspace
    // (device-scope atomicExch stores), then last-arriving chunk merges.
    // Candidates: <=CAP positives + 256 thread-zkeys (5 slots/lane). Keys
    // unique (anchor index embedded; pos high>=0x80000001 > zero 0x80000000).
    // All 13 slots written (zeros included) — merge skips zero keys.
#define MERGE_ROW(RR)                                                          \
    {                                                                          \
        if (act[RR]) {                                                         \
            int bi_r = b * n + i0 + RR;                                        \
            u64* dst = wslist + ((size_t)bi_r * NC + c0) * TOPK;               \
            int P = pc[RR];                                                    \
            if (P <= CAP) {                                                    \
                u64 s0 = (lane < P) ? posL[RR][lane] : 0ull;                   \
                u64 s1 = zdump[RR][lane];                                      \
                u64 s2 = zdump[RR][lane + 64];                                 \
                u64 s3 = zdump[RR][lane + 128];                                \
                u64 s4 = zdump[RR][lane + 192];                                \
                for (int round = 0; round < TOPK; ++round) {                   \
                    u64 m = s0;                                                \
                    if (s1 > m) m = s1;                                        \
                    if (s2 > m) m = s2;                                        \
                    if (s3 > m) m = s3;                                        \
                    if (s4 > m) m = s4;                                        \
                    for (int st = 32; st > 0; st >>= 1) {                      \
                        u64 o = __shfl_xor(m, st, 64);                         \
                        if (o > m) m = o;                                      \
                    }                                                          \
                    if (lane == 0) atomicExch(&dst[round], m);                 \
                    if (m != 0ull) {                                           \
                        if (s0 == m) s0 = 0ull;                                \
                        else if (s1 == m) s1 = 0ull;                           \
                        else if (s2 == m) s2 = 0ull;                           \
                        else if (s3 == m) s3 = 0ull;                           \
                        else if (s4 == m) s4 = 0ull;                           \
                    }                                                          \
                }                                                              \
            } else {                                                           \
                /* exact overflow fallback: 13-round iterative-max rescan */   \
                u64 last = 0xFFFFFFFFFFFFFFFFull;                              \
                for (int round = 0; round < TOPK; ++round) {                   \
                    u64 best = 0ull;                                           \
                    for (int aa = start + lane; aa < end; aa += 64) {          \
                        float2 ap2 = ac[aa];                                   \
                        float4 pp = pb[aa];                                    \
                        float mnv = fminf(fminf(ap2.x - g[RR].x,               \
                                                ap2.y - g[RR].y),              \
                                          fminf(g[RR].z - ap2.x,               \
                                                g[RR].w - ap2.y));             \
                        float iou = iou_fn(g[RR], pp);                         \
                        bool na = (mnv > 1e-9f) && (iou > 0.0f);               \
                        RowParams rp;                                          \
                        rp.av = rpav[RR]; rp.bar = rpbar[RR];                  \
                        rp.offc = rpoff[RR];                                   \
                        rp.mx = rpmx[RR]; rp.mn = rpmn[RR];                    \
                        float th = fabsf(ga[RR] - pa[aa]);                     \
                        float rr = ang_measure(rp, th);                        \
                        u64 zk = (0x80000000ull << 32) |                       \
                                 (u64)(0xFFFFFFFFu - (u32)aa);                 \
                        u64 key = 0ull;                                        \
                        if (na && rr > 0.0f) {                                 \
                            float s = scb[(size_t)aa * C + lab[RR]];           \
                            float v = align_fn(s, iou, rr);                    \
                            key = (v > 0.0f)                                   \
                                ? (((u64)ford(v) << 32) |                      \
                                   (u64)(0xFFFFFFFFu - (u32)aa))               \
                                : zk;                                          \
                        } else if (rr >= 0.0f) { key = zk; }                   \
                        if (key < last && key > best) best = key;              \
                    }                                                          \
                    u64 m = best;                                              \
                    for (int st = 32; st > 0; st >>= 1) {                      \
                        u64 o = __shfl_xor(m, st, 64);                         \
                        if (o > m) m = o;                                      \
                    }                                                          \
                    if (lane == 0) atomicExch(&dst[round], m);                 \
                    last = m;                                                  \
                }                                                              \
            }                                                                  \
            /* arrival: release-fence + count; last chunk merges the row */    \
            int old = 0;                                                       \
            if (lane == 0) {                                                   \
                __threadfence();                                               \
                old = atomicAdd(&rowdone[bi_r], 1);                            \
            }                                                                  \
            old = __shfl(old, 0, 64);                                          \
            if (old == NC - 1) {                                               \
                __threadfence();       /* acquire */                           \
                u64* src = wslist + (size_t)bi_r * (NC * TOPK);                \
                u64 ka = (lane < NC * TOPK)                                    \
                       ? atomicAdd(&src[lane], 0ull) : 0ull;                   \
                for (int round = 0; round < TOPK; ++round) {                   \
                    u64 m = ka;                                                \
                    for (int st = 32; st > 0; st >>= 1) {                      \
                        u64 o = __shfl_xor(m, st, 64);                         \
                        if (o > m) m = o;                                      \
                    }                                                          \
                    if (m == 0ull) break;  /* uniform across wave */           \
                    if (ka == m) {         /* unique owner lane */             \
                        ka = 0ull;                                             \
                        int aa = (int)(0xFFFFFFFFu -                           \
                                       (u32)(m & 0xFFFFFFFFull));              \
                        float2 ap2 = ac[aa];                                   \
                        float mnw = fminf(fminf(ap2.x - g[RR].x,               \
                                                ap2.y - g[RR].y),              \
                                          fminf(g[RR].z - ap2.x,               \
                                                g[RR].w - ap2.y));             \
                        if (mnw > 1e-9f) {                                     \
                            atomicAdd(&cnt[(size_t)b * A + aa], 1);            \
                            atomicMax(&assign1[(size_t)b * A + aa], i0 + RR);  \
                        }                                                      \
                    }                                                          \
                }                                                              \
            }                                                                  \
        }                                                                      \
    }

    if (wv == 0) { MERGE_ROW(0) }
    else if (wv == 1) { MERGE_ROW(1) }
    else if (wv == 2) { MERGE_ROW(2) }
    else { MERGE_ROW(3) }
#undef MERGE_ROW
}

__global__ __launch_bounds__(256)
void k2_resolve(const float* __restrict__ scores, const float* __restrict__ pbox,
                const float* __restrict__ pang, const int* __restrict__ glab,
                const float* __restrict__ gbox, const float* __restrict__ gang,
                const int* __restrict__ cnt, const int* __restrict__ assign1,
                int* __restrict__ assign, float* __restrict__ alignv,
                u32* __restrict__ pam, u32* __restrict__ pov,
                int bs, int A, int n, int C) {
    int t = blockIdx.x * blockDim.x + threadIdx.x;
    if (t >= bs * A) return;
    int b = t / A;
    int c = cnt[t];
    int asg = -1;
    float alv = 0.0f;
    if (c > 0) {
        float4 p = ((const float4*)pbox)[t];
        if (c == 1) {
            asg = assign1[t];
        } else {
            // reference: overlaps.argmax(1) over ALL gt rows, first-max tie-break
            float best = -1.0f;
            asg = 0;
            for (int i = 0; i < n; i++) {
                float4 gi = ((const float4*)gbox)[b * n + i];
                float io = iou_fn(gi, p);
                if (io > best) { best = io; asg = i; }
            }
        }
        float4 g = ((const float4*)gbox)[b * n + asg];
        RowParams rp = row_params(g);
        float iou = iou_fn(g, p);
        float th = fabsf(gang[b * n + asg] - pang[t]);
        float r = ang_measure(rp, th);
        float s = scores[(size_t)t * C + glab[b * n + asg]];
        alv = align_fn(s, iou, r);
        atomicMax(&pam[b * n + asg], ford(alv));
        atomicMax(&pov[b * n + asg], ford(iou));
    }
    assign[t] = asg;
    alignv[t] = alv;
}

// ---------------------------------------------------------------------------
// k3: outputs. ts zeros were pre-written by k1; only writes tlab/tbb/tang/fg
// (3.8 MB) plus ONE scattered ts element per fg anchor.
// ---------------------------------------------------------------------------
__global__ __launch_bounds__(256)
void k3_out(const int* __restrict__ glab, const float* __restrict__ gbox,
            const float* __restrict__ gang, const int* __restrict__ assign,
            const float* __restrict__ alignv, const u32* __restrict__ pam,
            const u32* __restrict__ pov, float* __restrict__ out,
            int bs, int A, int n, int C) {
    int t = blockIdx.x * blockDim.x + threadIdx.x;
    int BA = bs * A;
    if (t >= BA) return;
    int b = t / A;
    int asg = assign[t];
    bool fg = asg >= 0;
    int tgt = fg ? asg : 0;  // argmax of all-zero column -> row 0
    int lb = glab[b * n + tgt];
    if (lb < 0) lb = 0;

    out[t] = (float)lb;                                             // tlab
    ((float4*)(out + BA))[t] = ((const float4*)gbox)[b * n + tgt];  // tbb
    out[(size_t)BA * 5 + t] = gang[b * n + tgt];                    // tang
    out[(size_t)BA * 6 + (size_t)BA * C + t] = fg ? 1.0f : 0.0f;    // fg

    if (fg) {
        float pamv = funord(pam[b * n + asg]);
        float povv = funord(pov[b * n + asg]);
        float vv = (alignv[t] * povv) / (pamv + 1e-9f);
        // one_hot row: zeros pre-written by k1; single nonzero element.
        // (59 other gt rows contribute exactly 0 to the reference max.)
        out[(size_t)BA * 6 + (size_t)t * C + lb] = fmaxf(vv, 0.0f);
    }
}

extern "C" void kernel_launch(void* const* d_in, const int* in_sizes, int n_in,
                              void* d_out, int out_size, void* d_ws, size_t ws_size,
                              hipStream_t stream) {
    const float* scores = (const float*)d_in[0];
    const float* pbox = (const float*)d_in[1];
    const float* pang = (const float*)d_in[2];
    const float* anc = (const float*)d_in[3];
    const int* glab = (const int*)d_in[4];
    const float* gbox = (const float*)d_in[5];
    const float* gang = (const float*)d_in[6];
    const float* mgt = (const float*)d_in[7];

    const int C = 80;
    int A = in_sizes[3] / 2;
    int bs = in_sizes[0] / (A * C);
    int n = in_sizes[4] / bs;
    int BA = bs * A;
    int BN = bs * n;

    char* ws = (char*)d_ws;
    u64* wslist = (u64*)ws;     ws += sizeof(u64) * (size_t)BN * NC * TOPK;
    int* cnt = (int*)ws;        ws += sizeof(int) * (size_t)BA;
    int* assign1 = (int*)ws;    ws += sizeof(int) * (size_t)BA;
    int* assign = (int*)ws;     ws += sizeof(int) * (size_t)BA;
    float* alignv = (float*)ws; ws += sizeof(float) * (size_t)BA;
    u32* pam = (u32*)ws;        ws += sizeof(u32) * (size_t)BN;
    u32* pov = (u32*)ws;        ws += sizeof(u32) * (size_t)BN;
    int* rowdone = (int*)ws;    ws += sizeof(int) * (size_t)BN;

    int NG = (n + RPB - 1) / RPB;   // row groups per batch (15)

    k0_init<<<(BA + 255) / 256, 256, 0, stream>>>(cnt, assign1, pam, pov, rowdone, BA, BN);
    k1_topk<<<bs * NG * NC, 256, 0, stream>>>(scores, pbox, pang, anc, glab, gbox, gang,
                                              mgt, wslist, rowdone, cnt, assign1,
                                              (float*)d_out, bs, A, n, C);
    k2_resolve<<<(BA + 255) / 256, 256, 0, stream>>>(scores, pbox, pang, glab, gbox, gang,
                                                     cnt, assign1, assign, alignv, pam, pov,
                                                     bs, A, n, C);
    k3_out<<<(BA + 255) / 256, 256, 0, stream>>>(glab, gbox, gang, assign, alignv, pam, pov,
                                                 (float*)d_out, bs, A, n, C);
}

// Round 15
// 164.649 us; speedup vs baseline: 1.4556x; 1.4556x over previous
//
#include <hip/hip_runtime.h>
#include <math.h>

#define TOPK 13
#define PI_F 3.14159265358979323846f
#define K1_WAVES 4

typedef unsigned int u32;
typedef unsigned long long u64;

// monotone float -> uint mapping matching XLA total order
__device__ __forceinline__ u32 ford(float f) {
    u32 u = __float_as_uint(f);
    return (u & 0x80000000u) ? ~u : (u | 0x80000000u);
}
__device__ __forceinline__ float funord(u32 o) {
    u32 u = (o & 0x80000000u) ? (o & 0x7FFFFFFFu) : ~o;
    return __uint_as_float(u);
}

__device__ __forceinline__ float iou_fn(float4 g, float4 p) {
    float ltx = fmaxf(g.x, p.x), lty = fmaxf(g.y, p.y);
    float rbx = fminf(g.z, p.z), rby = fminf(g.w, p.w);
    float inter = fmaxf(rbx - ltx, 0.0f) * fmaxf(rby - lty, 0.0f);
    float a1 = fmaxf(g.z - g.x, 0.0f) * fmaxf(g.w - g.y, 0.0f);
    float a2 = fmaxf(p.z - p.x, 0.0f) * fmaxf(p.w - p.y, 0.0f);
    return inter / (((a1 + a2) - inter) + 1e-9f);
}

struct RowParams { float av, bar, offc, mx, mn; };

__device__ __forceinline__ RowParams row_params(float4 g) {
    float w = g.z - g.x, h = g.w - g.y;
    float ar = w / (h + 1e-5f);
    float ia = 1.0f / ar;
    RowParams rp;
    rp.av = ia / (2.0f - ia);
    rp.bar = 2.0f / ar;
    rp.offc = PI_F * (1.0f - 2.0f / (2.0f * ar));
    rp.mx = 0.5f + 0.5f * cosf(rp.offc);
    rp.mn = 0.5f + 0.5f * cosf(rp.bar * 90.0f / 180.0f * PI_F + rp.offc);
    return rp;
}

__device__ __forceinline__ float ang_measure(const RowParams& rp, float theta) {
    float cfv = 0.5f + 0.5f * cosf(rp.bar * theta / 180.0f * PI_F + rp.offc);
    float r = (cfv - rp.mn) / (rp.mx - rp.mn) * (1.0f - rp.av) + rp.av;
    return isnan(r) ? 0.0f : r;
}

// align in exact reference op order: (s**1 * iou**5) * ang**3, left-assoc
__device__ __forceinline__ float align_fn(float s, float iou, float r) {
    float iou2 = iou * iou;
    float iou5 = (iou2 * iou2) * iou;
    float r3 = (r * r) * r;
    return (s * iou5) * r3;
}

__global__ void k0_init(int* cnt, int* assign1, u32* pam, u32* pov, int BA, int BN) {
    int t = blockIdx.x * blockDim.x + threadIdx.x;
    if (t < BA) { cnt[t] = 0; assign1[t] = -1; }
    if (t < BN) { pam[t] = 0x80000000u; pov[t] = 0x80000000u; } // ord(+0.0f)
}

// ---------------------------------------------------------------------------
// k1: one block per (batch, gt-row), 4 waves. BEST-MEASURED CONFIGURATION
// (round 6: total 161.5 µs, k1 = 51 µs, absmax 0). 1-deep software pipeline
// on the streaming loads only (pbox/pang/anc, clamped, unconditional); the
// scattered score load stays on-demand in the rare path (r7 proved
// speculative prefetch moves FETCH_SIZE but not time). Hides the 43 MB ts
// zero-fill (fire-and-forget float4 stores — NO fences in this kernel, r14
// lesson) under the latency-bound scan, so k3 only writes 3.8 MB + one
// scattered element per fg anchor.
// Session accounting (r0-r14): ~120 µs of the total is fixed harness
// overhead (fillBufferAligned workspace re-poison 42.6 µs @ 78.8% HBM peak,
// input restores, launch gaps). The k1 alternatives measured: chunked+merge
// k1=42 µs but +k1m launch nets worse (r13); fence-based fold-in 109 µs
// (r14); LDS dbuf 64 µs (r9); 4-wide MLP 70 µs (r8). This structure is the
// measured optimum of the set.
// ---------------------------------------------------------------------------
__global__ __launch_bounds__(256)
void k1_topk(const float* __restrict__ scores, const float* __restrict__ pbox,
             const float* __restrict__ pang, const float* __restrict__ anc,
             const int* __restrict__ glab, const float* __restrict__ gbox,
             const float* __restrict__ gang, const float* __restrict__ mgt,
             int* __restrict__ cnt, int* __restrict__ assign1,
             float* __restrict__ out,
             int bs, int A, int n, int C) {
    int j = blockIdx.x;
    // XCD clustering: blocks of the same batch land on the same XCD (j % 8 == b % 8)
    int b = j % bs;
    int i = j / bs;
    int bi = b * n + i;
    int tid = threadIdx.x;
    int BA = bs * A;

    // ts zero-fill chunk for this block (hidden under the anchor scan)
    int nF4 = BA * (C / 4);
    int zCH = (nF4 + gridDim.x - 1) / gridDim.x;
    int zBeg = j * zCH + tid;
    int zEnd = min(j * zCH + zCH, nF4);
    float4* tsf4 = (float4*)(out + (size_t)BA * 6);
    const float4 z4 = make_float4(0.0f, 0.0f, 0.0f, 0.0f);

    float mg = mgt[bi];
    if (!(mg > 0.0f)) {
        // masked row contributes no candidates, but still owns its ts chunk
        for (; zBeg < zEnd; zBeg += 256) tsf4[zBeg] = z4;
        return;
    }

    float4 g = ((const float4*)gbox)[bi];
    int lab = glab[bi];
    float ga = gang[bi];
    RowParams rp = row_params(g);

    const float4* pb = ((const float4*)pbox) + (size_t)b * A;
    const float* pa = pang + (size_t)b * A;
    const float2* ac = (const float2*)anc;
    const float* sc = scores + (size_t)b * A * C + lab;

    u64 arr[TOPK];
#pragma unroll
    for (int jj = 0; jj < TOPK; jj++) arr[jj] = 0ull;
    u64 zkey = 0ull;  // thread's lowest-index exact-+0 candidate

    // prologue: stage iteration 0 (tid < 256 <= A, so a is valid)
    int a = tid;
    float4 p = pb[a];
    float pav = pa[a];
    float2 apt = ac[a];
    float mnv = fminf(fminf(apt.x - g.x, apt.y - g.y), fminf(g.z - apt.x, g.w - apt.y));

    // Exactness of the conditional-r path (reference v = align*in_gts,
    // align = (s*iou^5)*r^3, s>=0, iou>=0, r finite after NaN-replace):
    //  - !inGt or iou==0  -> v = +/-0 with sign(r); selectable only if +0.
    //  - inGt && iou>0    -> r>0: v = align (insert if >0, else +0 cand);
    //                       r==0: +0 cand; r<0: v<0 never selectable.
    //  sign(r) only consumed while zkey unset -> cosf skipped afterwards.
    int nit = (A + 255) >> 8;          // uniform trip count; tail guarded by `valid`
    int clampA = A - 1;
    for (int it = 0; it < nit; ++it) {
        // stage iteration it+1 (clamped, unconditional -> pipelineable)
        int an = a + 256;
        int can = min(an, clampA);
        float4 p2 = pb[can];
        float pav2 = pa[can];
        float2 apt2 = ac[can];
        // hidden zero-fill store (independent, fire-and-forget)
        if (zBeg < zEnd) { tsf4[zBeg] = z4; zBeg += 256; }
        float mnv2 = fminf(fminf(apt2.x - g.x, apt2.y - g.y),
                           fminf(g.z - apt2.x, g.w - apt2.y));

        // consume iteration it (operands already resident)
        bool valid = a < A;
        float iou = iou_fn(g, p);
        bool needAlign = (mnv > 1e-9f) && (iou > 0.0f) && valid;
        if (needAlign || (zkey == 0ull && valid)) {
            float th = fabsf(ga - pav);
            float r = ang_measure(rp, th);
            bool zeroCand;
            if (needAlign && r > 0.0f) {
                float s = sc[(size_t)a * C];   // scattered load, rare path only
                float v = align_fn(s, iou, r);
                if (v > 0.0f) {
                    zeroCand = false;
                    u64 key = ((u64)ford(v) << 32) | (u64)(0xFFFFFFFFu - (u32)a);
                    if (key > arr[TOPK - 1]) {
#pragma unroll
                        for (int jj = 0; jj < TOPK; jj++) {
                            u64 hi = arr[jj] > key ? arr[jj] : key;
                            u64 lo = arr[jj] > key ? key : arr[jj];
                            arr[jj] = hi;
                            key = lo;
                        }
                    }
                } else {
                    zeroCand = true;  // s==0 or iou^5 underflow -> v == +0 exactly
                }
            } else {
                zeroCand = (r >= 0.0f);  // v == sign(r)*0; only +0 is selectable
            }
            if (zeroCand && zkey == 0ull) {
                zkey = (0x80000000ull << 32) | (u64)(0xFFFFFFFFu - (u32)a);
            }
        }
        a = an; p = p2; pav = pav2; mnv = mnv2;
    }
    for (; zBeg < zEnd; zBeg += 256) tsf4[zBeg] = z4;  // drain (normally no-op)
    // merge the single zero candidate (sufficient per thread: the 13
    // lowest-index zero candidates land on distinct threads at stride 256)
    if (zkey > arr[TOPK - 1]) {
        u64 key = zkey;
#pragma unroll
        for (int jj = 0; jj < TOPK; jj++) {
            u64 hi = arr[jj] > key ? arr[jj] : key;
            u64 lo = arr[jj] > key ? key : arr[jj];
            arr[jj] = hi;
            key = lo;
        }
    }

    // Phase 1: per-wave top-13 (no barriers; keys unique, 0 = empty).
    __shared__ u64 wtop[K1_WAVES * TOPK];
    int lane = tid & 63, wv = tid >> 6;
    for (int round = 0; round < TOPK; round++) {
        u64 m = arr[0];
#pragma unroll
        for (int st = 32; st > 0; st >>= 1) {
            u64 o = __shfl_xor(m, st, 64);
            if (o > m) m = o;
        }
        if (lane == 0) wtop[wv * TOPK + round] = m;
        if (arr[0] == m && m != 0ull) {  // unique winner pops its head
#pragma unroll
            for (int jj = 0; jj < TOPK - 1; jj++) arr[jj] = arr[jj + 1];
            arr[TOPK - 1] = 0ull;
        }
    }
    __syncthreads();

    // Phase 2: wave 0 merges the 4 sorted 13-lists (52 keys, one per lane)
    // and fires the atomics for the block top-13.
    if (wv == 0) {
        const int NK = K1_WAVES * TOPK;  // 52
        u64 ka = (lane < NK) ? wtop[lane] : 0ull;
        for (int round = 0; round < TOPK; round++) {
            u64 m = ka;
#pragma unroll
            for (int st = 32; st > 0; st >>= 1) {
                u64 o = __shfl_xor(m, st, 64);
                if (o > m) m = o;
            }
            if (m == 0ull) break;        // uniform across wave 0 -> safe
            if (ka == m) {               // unique owner lane processes the winner
                ka = 0ull;
                int aa = (int)(0xFFFFFFFFu - (u32)(m & 0xFFFFFFFFull));
                float2 ap2 = ac[aa];
                float mnw = fminf(fminf(ap2.x - g.x, ap2.y - g.y),
                                  fminf(g.z - ap2.x, g.w - ap2.y));
                if (mnw > 1e-9f) {  // mask_pos = mask_topk * in_gts * mask_gt
                    atomicAdd(&cnt[(size_t)b * A + aa], 1);
                    atomicMax(&assign1[(size_t)b * A + aa], i);
                }
            }
        }
    }
}

__global__ __launch_bounds__(256)
void k2_resolve(const float* __restrict__ scores, const float* __restrict__ pbox,
                const float* __restrict__ pang, const int* __restrict__ glab,
                const float* __restrict__ gbox, const float* __restrict__ gang,
                const int* __restrict__ cnt, const int* __restrict__ assign1,
                int* __restrict__ assign, float* __restrict__ alignv,
                u32* __restrict__ pam, u32* __restrict__ pov,
                int bs, int A, int n, int C) {
    int t = blockIdx.x * blockDim.x + threadIdx.x;
    if (t >= bs * A) return;
    int b = t / A;
    int c = cnt[t];
    int asg = -1;
    float alv = 0.0f;
    if (c > 0) {
        float4 p = ((const float4*)pbox)[t];
        if (c == 1) {
            asg = assign1[t];
        } else {
            // reference: overlaps.argmax(1) over ALL gt rows, first-max tie-break
            float best = -1.0f;
            asg = 0;
            for (int i = 0; i < n; i++) {
                float4 gi = ((const float4*)gbox)[b * n + i];
                float io = iou_fn(gi, p);
                if (io > best) { best = io; asg = i; }
            }
        }
        float4 g = ((const float4*)gbox)[b * n + asg];
        RowParams rp = row_params(g);
        float iou = iou_fn(g, p);
        float th = fabsf(gang[b * n + asg] - pang[t]);
        float r = ang_measure(rp, th);
        float s = scores[(size_t)t * C + glab[b * n + asg]];
        alv = align_fn(s, iou, r);
        atomicMax(&pam[b * n + asg], ford(alv));
        atomicMax(&pov[b * n + asg], ford(iou));
    }
    assign[t] = asg;
    alignv[t] = alv;
}

// ---------------------------------------------------------------------------
// k3: outputs. ts zeros were pre-written by k1; only writes tlab/tbb/tang/fg
// (3.8 MB) plus ONE scattered ts element per fg anchor.
// ---------------------------------------------------------------------------
__global__ __launch_bounds__(256)
void k3_out(const int* __restrict__ glab, const float* __restrict__ gbox,
            const float* __restrict__ gang, const int* __restrict__ assign,
            const float* __restrict__ alignv, const u32* __restrict__ pam,
            const u32* __restrict__ pov, float* __restrict__ out,
            int bs, int A, int n, int C) {
    int t = blockIdx.x * blockDim.x + threadIdx.x;
    int BA = bs * A;
    if (t >= BA) return;
    int b = t / A;
    int asg = assign[t];
    bool fg = asg >= 0;
    int tgt = fg ? asg : 0;  // argmax of all-zero column -> row 0
    int lb = glab[b * n + tgt];
    if (lb < 0) lb = 0;

    out[t] = (float)lb;                                             // tlab
    ((float4*)(out + BA))[t] = ((const float4*)gbox)[b * n + tgt];  // tbb
    out[(size_t)BA * 5 + t] = gang[b * n + tgt];                    // tang
    out[(size_t)BA * 6 + (size_t)BA * C + t] = fg ? 1.0f : 0.0f;    // fg

    if (fg) {
        float pamv = funord(pam[b * n + asg]);
        float povv = funord(pov[b * n + asg]);
        float vv = (alignv[t] * povv) / (pamv + 1e-9f);
        // one_hot row: zeros pre-written by k1; single nonzero element.
        // (59 other gt rows contribute exactly 0 to the reference max.)
        out[(size_t)BA * 6 + (size_t)t * C + lb] = fmaxf(vv, 0.0f);
    }
}

extern "C" void kernel_launch(void* const* d_in, const int* in_sizes, int n_in,
                              void* d_out, int out_size, void* d_ws, size_t ws_size,
                              hipStream_t stream) {
    const float* scores = (const float*)d_in[0];
    const float* pbox = (const float*)d_in[1];
    const float* pang = (const float*)d_in[2];
    const float* anc = (const float*)d_in[3];
    const int* glab = (const int*)d_in[4];
    const float* gbox = (const float*)d_in[5];
    const float* gang = (const float*)d_in[6];
    const float* mgt = (const float*)d_in[7];

    const int C = 80;
    int A = in_sizes[3] / 2;
    int bs = in_sizes[0] / (A * C);
    int n = in_sizes[4] / bs;
    int BA = bs * A;
    int BN = bs * n;

    char* ws = (char*)d_ws;
    int* cnt = (int*)ws;        ws += sizeof(int) * (size_t)BA;
    int* assign1 = (int*)ws;    ws += sizeof(int) * (size_t)BA;
    int* assign = (int*)ws;     ws += sizeof(int) * (size_t)BA;
    float* alignv = (float*)ws; ws += sizeof(float) * (size_t)BA;
    u32* pam = (u32*)ws;        ws += sizeof(u32) * (size_t)BN;
    u32* pov = (u32*)ws;        ws += sizeof(u32) * (size_t)BN;

    k0_init<<<(BA + 255) / 256, 256, 0, stream>>>(cnt, assign1, pam, pov, BA, BN);
    k1_topk<<<BN, 256, 0, stream>>>(scores, pbox, pang, anc, glab, gbox, gang, mgt,
                                    cnt, assign1, (float*)d_out, bs, A, n, C);
    k2_resolve<<<(BA + 255) / 256, 256, 0, stream>>>(scores, pbox, pang, glab, gbox, gang,
                                                     cnt, assign1, assign, alignv, pam, pov,
                                                     bs, A, n, C);
    k3_out<<<(BA + 255) / 256, 256, 0, stream>>>(glab, gbox, gang, assign, alignv, pam, pov,
                                                 (float*)d_out, bs, A, n, C);
}